// Round 7
// baseline (221.460 us; speedup 1.0000x reference)
//
#include <hip/hip_runtime.h>

// GraphAttentionLayer: B=1, N=4096, F=256, H=8, U=64
//
// e_src cancels in softmax over j =>
//   out[i, u*8+h] = relu( (A @ (w*h))[i, h*64+u] / (A @ w)[i, h] ),  w = exp(e_dst)
// => ONE dense GEMM  C = A(4096x4096) x G(4096x544), G = [w*h (512) | w (8) | 0 (24)]
//
// R7 = R5 (best verified: 173 us, gemm 64.9) with ONE change: split-K Z=4->8
// (2 blocks/CU, 4 waves/SIMD) to double latency hiding for the proven
// high-MLP inner loop. R6 showed that cutting per-wave loads at 2 waves/SIMD
// REDUCES the MLP that hides L2 latency -> keep R5's 10-loads/dstep shape.
//
// Gtp layout (HW-verified): tile (tk=k>>4, nt=n>>5), id=tk*17+nt, 1024 B:
//   u16[ id*512 + ((n&31) + 32*((k&15)>>3))*8 + (k&7) ]; B-frag(lane)=16B at id*1024+lane*16.
//
// ws: P @0 (8,912,896 B) | Gtp @8912896 (4,456,448 B)

typedef unsigned short u16;
typedef unsigned int   u32;
typedef __attribute__((ext_vector_type(8)))  short  short8;    // 8 bf16 (4 VGPR)
typedef __attribute__((ext_vector_type(16))) float  floatx16;  // 32x32 MFMA acc
typedef __attribute__((ext_vector_type(8)))  unsigned short u16x8;
typedef __attribute__((ext_vector_type(4)))  unsigned short u16x4;

__device__ __forceinline__ u16 f2bf(float x) {
  u32 u = __float_as_uint(x);
  u += 0x7fffu + ((u >> 16) & 1u);   // RNE
  return (u16)(u >> 16);
}

__device__ __forceinline__ void async_ld16(const void* g, void* l) {
  __builtin_amdgcn_global_load_lds((const __attribute__((address_space(1))) void*)g,
                                   (__attribute__((address_space(3))) void*)l,
                                   16, 0, 0);
}

// ---------------------------------------------------------------------------
// Kernel 1: h = X@W (fp32, exact), e_dst -> w = exp, write Gtp (B-frag layout).
// Block: 32 j-rows x 128 c-cols (2 whole heads => e-sums block-local).
// Grid (128, 4) = 512 blocks = 2/CU. Also zeroes P. (R5 verbatim.)
// ---------------------------------------------------------------------------
__global__ __launch_bounds__(256) void k_hg(const float* __restrict__ X,
                                            const float* __restrict__ W,
                                            const float* __restrict__ av,
                                            u16* __restrict__ Gtp,
                                            float* __restrict__ P) {
  __shared__ __align__(16) float Wc[64 * 128];   // 32 KB
  __shared__ __align__(16) float xs[64 * 36];    // 9 KB (pad 36 breaks stride)
  __shared__ float eL[64];
  __shared__ float w8L[64];
  const int t  = threadIdx.x;
  const int j0 = blockIdx.x * 32;
  const int y  = blockIdx.y;           // heads 2y, 2y+1
  const int c0 = y * 128;
  const int cq = t & 31, tj = t >> 5;

  // zero this block's P slab
  {
    float4* P4 = (float4*)P;
    const int base = ((int)blockIdx.y * 128 + (int)blockIdx.x) * 1088;
    float4 z = {0.f, 0.f, 0.f, 0.f};
#pragma unroll
    for (int q = 0; q < 4; ++q) P4[base + q * 256 + t] = z;
    if (t < 64) P4[base + 1024 + t] = z;
  }
  if (t < 64) eL[t] = 0.f;

  float acc[4][4];
#pragma unroll
  for (int a = 0; a < 4; ++a)
#pragma unroll
    for (int b = 0; b < 4; ++b) acc[a][b] = 0.f;

  const int xjj = t >> 3, xoff = (t & 7) * 8;

  for (int cc = 0; cc < 4; ++cc) {
#pragma unroll
    for (int l = 0; l < 8; ++l) {
      int id = l * 256 + t;
      int kk = id >> 5, ch = id & 31;
      async_ld16(W + (size_t)(cc * 64 + kk) * 512 + c0 + ch * 4,
                 (char*)&Wc[0] + (size_t)(l * 256 + (t & 192)) * 16);
    }
    {
      const float* xp = X + (size_t)(j0 + xjj) * 256 + cc * 64 + xoff;
      float4 v0 = *(const float4*)xp;
      float4 v1 = *(const float4*)(xp + 4);
      xs[(xoff + 0) * 36 + xjj] = v0.x; xs[(xoff + 1) * 36 + xjj] = v0.y;
      xs[(xoff + 2) * 36 + xjj] = v0.z; xs[(xoff + 3) * 36 + xjj] = v0.w;
      xs[(xoff + 4) * 36 + xjj] = v1.x; xs[(xoff + 5) * 36 + xjj] = v1.y;
      xs[(xoff + 6) * 36 + xjj] = v1.z; xs[(xoff + 7) * 36 + xjj] = v1.w;
    }
    __syncthreads();
#pragma unroll 4
    for (int kk = 0; kk < 64; ++kk) {
      float4 w4 = *(const float4*)(&Wc[kk * 128 + cq * 4]);
      float4 xa = *(const float4*)(&xs[kk * 36 + tj * 4]);   // broadcast
      acc[0][0] += xa.x * w4.x; acc[0][1] += xa.x * w4.y; acc[0][2] += xa.x * w4.z; acc[0][3] += xa.x * w4.w;
      acc[1][0] += xa.y * w4.x; acc[1][1] += xa.y * w4.y; acc[1][2] += xa.y * w4.z; acc[1][3] += xa.y * w4.w;
      acc[2][0] += xa.z * w4.x; acc[2][1] += xa.z * w4.y; acc[2][2] += xa.z * w4.z; acc[2][3] += xa.z * w4.w;
      acc[3][0] += xa.w * w4.x; acc[3][1] += xa.w * w4.y; acc[3][2] += xa.w * w4.z; acc[3][3] += xa.w * w4.w;
    }
    __syncthreads();
  }

  // e_dst partials (2 block-local heads)
  const int lh = cq >> 4;
  {
    const float4 ad = *(const float4*)(av + 64 + (cq & 15) * 4);
#pragma unroll
    for (int jv = 0; jv < 4; ++jv) {
      float ep = acc[jv][0] * ad.x + acc[jv][1] * ad.y + acc[jv][2] * ad.z + acc[jv][3] * ad.w;
      atomicAdd(&eL[(tj * 4 + jv) * 2 + lh], ep);
    }
  }
  __syncthreads();
  if (t < 64) {
    float e = fminf(30.f, fmaxf(-30.f, eL[t]));
    w8L[t] = __expf(e);
  }
  __syncthreads();

  // scaled bf16 stores in B-frag layout
  const int tk  = (j0 >> 4) + (tj >> 2);
  const int khh = (tj >> 1) & 1;
  const int jlo = (tj & 1) * 4;
#pragma unroll
  for (int cv = 0; cv < 4; ++cv) {
    int n  = c0 + cq * 4 + cv;
    int nt = n >> 5;
    u16x4 o;
#pragma unroll
    for (int jv = 0; jv < 4; ++jv)
      o[jv] = f2bf(acc[jv][cv] * w8L[(tj * 4 + jv) * 2 + lh]);
    *(u16x4*)(Gtp + (size_t)(tk * 17 + nt) * 512 + ((n & 31) + 32 * khh) * 8 + jlo) = o;
  }
  // den rows (n = 512 + h, this block's 2 heads x 32 rows)
  if (t < 64) {
    int jj = t >> 1, lh2 = t & 1, h = 2 * y + lh2, j = j0 + jj;
    Gtp[(size_t)((j >> 4) * 17 + 16) * 512 + (h + 32 * ((jj & 15) >> 3)) * 8 + (jj & 7)] =
        f2bf(w8L[jj * 2 + lh2]);
  }
  // zero pad (n in [520,544)): slots [8,32) and [40,64) of tile nt=16
  if (y == 3 && t < 96) {
    int tk2 = t / 48, r = t - tk2 * 48;
    int slot = (r < 24) ? (8 + r) : (16 + r);
    u16x8 z = {0, 0, 0, 0, 0, 0, 0, 0};
    *(u16x8*)(Gtp + (size_t)(((j0 >> 4) + tk2) * 17 + 16) * 512 + slot * 8) = z;
  }
}

// ---------------------------------------------------------------------------
// Kernel 2: C += A(fp32,{0,1}) x G^T via 32x32x16 bf16 MFMA, atomicAdd into P.
// R5 structure verbatim (high-MLP: 10 B-load streams/dstep per wave), but
// split-K Z=8: grid (64,8) = 512 blocks = 2 blocks/CU = 4 waves/SIMD.
// kslice=512 -> 2 K-chunks of 256, dbuf LDS (2x32 KB).
// ---------------------------------------------------------------------------
__global__ __launch_bounds__(512, 4) void k_gemm(const float* __restrict__ A,
                                                 const u16* __restrict__ Gtp,
                                                 float* __restrict__ P) {
  __shared__ __align__(16) u16 As[2][64 * 256];  // 2 x 32 KB
  const int t    = threadIdx.x;
  const int i0   = blockIdx.x * 64;
  const int kt0  = blockIdx.y * 512;
  const int w    = t >> 6, lane = t & 63;
  const int wr   = w >> 2, wc = w & 3;
  const int ml   = lane & 31, kh = lane >> 5;

  floatx16 acc[5];
#pragma unroll
  for (int q = 0; q < 5; ++q)
#pragma unroll
    for (int r = 0; r < 16; ++r) acc[q][r] = 0.f;

  // A staging: thread -> row ar (0..63), q-th float4 at k = (t&7)*4 + q*32
  const int ar  = t >> 3;
  const int af  = (t & 7) * 4;
  const float* pa = A + (size_t)(i0 + ar) * 4096 + kt0 + af;
  const int sbase = ar * 256 + (t & 1) * 4;   // + swizzled chunk*8
  const int scb   = (t & 7) >> 1;             // chunk = q*4 + scb
  const int arx   = ar & 7;

  // A-frag reads: row m = wr*32+ml, chunk c -> physical c^(ml&7)
  const int arow = (wr * 32 + ml) * 256;
  const int mx   = ml & 7;

  int nta[5];
#pragma unroll
  for (int q = 0; q < 5; ++q) { int v = wc + 4 * q; nta[q] = v < 17 ? v : 16; }

  float4 areg[8];
#pragma unroll
  for (int q = 0; q < 8; ++q) areg[q] = *(const float4*)(pa + q * 32);
#pragma unroll
  for (int q = 0; q < 8; ++q) {
    u16x4 v = {f2bf(areg[q].x), f2bf(areg[q].y), f2bf(areg[q].z), f2bf(areg[q].w)};
    *(u16x4*)(&As[0][sbase + ((q * 4 + scb) ^ arx) * 8]) = v;
  }
  __syncthreads();

  for (int cc = 0; cc < 2; ++cc) {
    const int cb = cc & 1;
    if (cc < 1) {                    // prefetch next chunk early (hidden by compute)
#pragma unroll
      for (int q = 0; q < 8; ++q)
        areg[q] = *(const float4*)(pa + (cc + 1) * 256 + q * 32);
    }
    const int ktb = (kt0 >> 4) + cc * 16;
#pragma unroll 2
    for (int ds = 0; ds < 8; ++ds) {
      short8 b0[5], b1[5];
#pragma unroll
      for (int q = 0; q < 5; ++q) {
        b0[q] = *(const short8*)(Gtp + (size_t)((ktb + ds * 2) * 17 + nta[q]) * 512 + lane * 8);
        b1[q] = *(const short8*)(Gtp + (size_t)((ktb + ds * 2 + 1) * 17 + nta[q]) * 512 + lane * 8);
      }
      short8 a0 = *(const short8*)(&As[cb][arow + ((ds * 4 + kh) ^ mx) * 8]);
      short8 a1 = *(const short8*)(&As[cb][arow + ((ds * 4 + 2 + kh) ^ mx) * 8]);
#pragma unroll
      for (int q = 0; q < 5; ++q)
        acc[q] = __builtin_amdgcn_mfma_f32_32x32x16_bf16(a0, b0[q], acc[q], 0, 0, 0);
#pragma unroll
      for (int q = 0; q < 5; ++q)
        acc[q] = __builtin_amdgcn_mfma_f32_32x32x16_bf16(a1, b1[q], acc[q], 0, 0, 0);
    }
    if (cc < 1) {
      __syncthreads();               // readers of other buffer done
#pragma unroll
      for (int q = 0; q < 8; ++q) {
        u16x4 v = {f2bf(areg[q].x), f2bf(areg[q].y), f2bf(areg[q].z), f2bf(areg[q].w)};
        *(u16x4*)(&As[cb ^ 1][sbase + ((q * 4 + scb) ^ arx) * 8]) = v;
      }
      __syncthreads();               // writes visible
    }
  }

  // epilogue: C/D layout col=lane&31, row=(r&3)+8*(r>>2)+4*(lane>>5); atomics
  const int rbase = i0 + wr * 32 + 4 * kh;
#pragma unroll
  for (int q = 0; q < 5; ++q) {
    int n = (wc + 4 * q) * 32 + ml;
    if (n < 520) {
#pragma unroll
      for (int r = 0; r < 16; ++r) {
        int row = rbase + (r & 3) + 8 * (r >> 2);
        atomicAdd(P + (size_t)row * 544 + n, acc[q][r]);
      }
    }
  }
}

// ---------------------------------------------------------------------------
// Kernel 3: out[i, u*8+h] = relu( P[i][h*64+u] / P[i][512+h] ). 2 rows/block.
// ---------------------------------------------------------------------------
__global__ __launch_bounds__(256) void k_out(const float* __restrict__ P,
                                             float* __restrict__ out) {
  __shared__ float ps[2][544];
  const int t    = threadIdx.x;
  const int half = t >> 7, lt = t & 127;
  const int i    = blockIdx.x * 2 + half;
  const float* pr = P + (size_t)i * 544;
  for (int q = lt; q < 544; q += 128) ps[half][q] = pr[q];
  __syncthreads();
  for (int c = lt; c < 512; c += 128) {           // c = u*8 + h
    int u = c >> 3, hd = c & 7;
    float o = ps[half][hd * 64 + u] / ps[half][512 + hd];
    out[(size_t)i * 512 + c] = fmaxf(o, 0.f);
  }
}

extern "C" void kernel_launch(void* const* d_in, const int* in_sizes, int n_in,
                              void* d_out, int out_size, void* d_ws, size_t ws_size,
                              hipStream_t stream) {
  const float* X  = (const float*)d_in[0];
  const float* A  = (const float*)d_in[1];
  const float* W  = (const float*)d_in[2];
  const float* av = (const float*)d_in[3];
  float* out = (float*)d_out;
  char*  ws  = (char*)d_ws;

  float* P   = (float*)ws;                 // 4096*544*4
  u16*   Gtp = (u16*)(ws + 8912896);       // 256*17 tiles * 1024 B

  k_hg<<<dim3(128, 4), 256, 0, stream>>>(X, W, av, Gtp, P);
  k_gemm<<<dim3(64, 8), 512, 0, stream>>>(A, Gtp, P);
  k_out<<<2048, 256, 0, stream>>>(P, out);
}

// Round 8
// 197.466 us; speedup vs baseline: 1.1215x; 1.1215x over previous
//
#include <hip/hip_runtime.h>

// GraphAttentionLayer: B=1, N=4096, F=256, H=8, U=64
//
// e_src cancels in softmax over j =>
//   out[i, u*8+h] = relu( (A @ (w*h))[i, h*64+u] / (A @ w)[i, h] ),  w = exp(e_dst)
// => ONE dense GEMM  C = A(4096x4096) x G(4096x544), G = [w*h (512) | w (8) | 0 (24)]
//
// R8 = R7 with ONE token fixed: __launch_bounds__(512,2) instead of (512,4).
// R7's (512,4) forced a 64-VGPR cap < the ~80 needed for acc[5] alone ->
// scratch spills (WRITE 107 MB vs 68 expected, FETCH +20 MB). R5 measured
// 108 VGPR under (512,2): 108<=128 -> 4 waves/SIMD at Z=8 WITHOUT forcing.
//
// Gtp layout (HW-verified): tile (tk=k>>4, nt=n>>5), id=tk*17+nt, 1024 B:
//   u16[ id*512 + ((n&31) + 32*((k&15)>>3))*8 + (k&7) ]; B-frag(lane)=16B at id*1024+lane*16.
//
// ws: P @0 (8,912,896 B) | Gtp @8912896 (4,456,448 B)

typedef unsigned short u16;
typedef unsigned int   u32;
typedef __attribute__((ext_vector_type(8)))  short  short8;    // 8 bf16 (4 VGPR)
typedef __attribute__((ext_vector_type(16))) float  floatx16;  // 32x32 MFMA acc
typedef __attribute__((ext_vector_type(8)))  unsigned short u16x8;
typedef __attribute__((ext_vector_type(4)))  unsigned short u16x4;

__device__ __forceinline__ u16 f2bf(float x) {
  u32 u = __float_as_uint(x);
  u += 0x7fffu + ((u >> 16) & 1u);   // RNE
  return (u16)(u >> 16);
}

__device__ __forceinline__ void async_ld16(const void* g, void* l) {
  __builtin_amdgcn_global_load_lds((const __attribute__((address_space(1))) void*)g,
                                   (__attribute__((address_space(3))) void*)l,
                                   16, 0, 0);
}

// ---------------------------------------------------------------------------
// Kernel 1: h = X@W (fp32, exact), e_dst -> w = exp, write Gtp (B-frag layout).
// Block: 32 j-rows x 128 c-cols (2 whole heads => e-sums block-local).
// Grid (128, 4) = 512 blocks = 2/CU. Also zeroes P. (R5 verbatim.)
// ---------------------------------------------------------------------------
__global__ __launch_bounds__(256) void k_hg(const float* __restrict__ X,
                                            const float* __restrict__ W,
                                            const float* __restrict__ av,
                                            u16* __restrict__ Gtp,
                                            float* __restrict__ P) {
  __shared__ __align__(16) float Wc[64 * 128];   // 32 KB
  __shared__ __align__(16) float xs[64 * 36];    // 9 KB (pad 36 breaks stride)
  __shared__ float eL[64];
  __shared__ float w8L[64];
  const int t  = threadIdx.x;
  const int j0 = blockIdx.x * 32;
  const int y  = blockIdx.y;           // heads 2y, 2y+1
  const int c0 = y * 128;
  const int cq = t & 31, tj = t >> 5;

  // zero this block's P slab
  {
    float4* P4 = (float4*)P;
    const int base = ((int)blockIdx.y * 128 + (int)blockIdx.x) * 1088;
    float4 z = {0.f, 0.f, 0.f, 0.f};
#pragma unroll
    for (int q = 0; q < 4; ++q) P4[base + q * 256 + t] = z;
    if (t < 64) P4[base + 1024 + t] = z;
  }
  if (t < 64) eL[t] = 0.f;

  float acc[4][4];
#pragma unroll
  for (int a = 0; a < 4; ++a)
#pragma unroll
    for (int b = 0; b < 4; ++b) acc[a][b] = 0.f;

  const int xjj = t >> 3, xoff = (t & 7) * 8;

  for (int cc = 0; cc < 4; ++cc) {
#pragma unroll
    for (int l = 0; l < 8; ++l) {
      int id = l * 256 + t;
      int kk = id >> 5, ch = id & 31;
      async_ld16(W + (size_t)(cc * 64 + kk) * 512 + c0 + ch * 4,
                 (char*)&Wc[0] + (size_t)(l * 256 + (t & 192)) * 16);
    }
    {
      const float* xp = X + (size_t)(j0 + xjj) * 256 + cc * 64 + xoff;
      float4 v0 = *(const float4*)xp;
      float4 v1 = *(const float4*)(xp + 4);
      xs[(xoff + 0) * 36 + xjj] = v0.x; xs[(xoff + 1) * 36 + xjj] = v0.y;
      xs[(xoff + 2) * 36 + xjj] = v0.z; xs[(xoff + 3) * 36 + xjj] = v0.w;
      xs[(xoff + 4) * 36 + xjj] = v1.x; xs[(xoff + 5) * 36 + xjj] = v1.y;
      xs[(xoff + 6) * 36 + xjj] = v1.z; xs[(xoff + 7) * 36 + xjj] = v1.w;
    }
    __syncthreads();
#pragma unroll 4
    for (int kk = 0; kk < 64; ++kk) {
      float4 w4 = *(const float4*)(&Wc[kk * 128 + cq * 4]);
      float4 xa = *(const float4*)(&xs[kk * 36 + tj * 4]);   // broadcast
      acc[0][0] += xa.x * w4.x; acc[0][1] += xa.x * w4.y; acc[0][2] += xa.x * w4.z; acc[0][3] += xa.x * w4.w;
      acc[1][0] += xa.y * w4.x; acc[1][1] += xa.y * w4.y; acc[1][2] += xa.y * w4.z; acc[1][3] += xa.y * w4.w;
      acc[2][0] += xa.z * w4.x; acc[2][1] += xa.z * w4.y; acc[2][2] += xa.z * w4.z; acc[2][3] += xa.z * w4.w;
      acc[3][0] += xa.w * w4.x; acc[3][1] += xa.w * w4.y; acc[3][2] += xa.w * w4.z; acc[3][3] += xa.w * w4.w;
    }
    __syncthreads();
  }

  // e_dst partials (2 block-local heads)
  const int lh = cq >> 4;
  {
    const float4 ad = *(const float4*)(av + 64 + (cq & 15) * 4);
#pragma unroll
    for (int jv = 0; jv < 4; ++jv) {
      float ep = acc[jv][0] * ad.x + acc[jv][1] * ad.y + acc[jv][2] * ad.z + acc[jv][3] * ad.w;
      atomicAdd(&eL[(tj * 4 + jv) * 2 + lh], ep);
    }
  }
  __syncthreads();
  if (t < 64) {
    float e = fminf(30.f, fmaxf(-30.f, eL[t]));
    w8L[t] = __expf(e);
  }
  __syncthreads();

  // scaled bf16 stores in B-frag layout
  const int tk  = (j0 >> 4) + (tj >> 2);
  const int khh = (tj >> 1) & 1;
  const int jlo = (tj & 1) * 4;
#pragma unroll
  for (int cv = 0; cv < 4; ++cv) {
    int n  = c0 + cq * 4 + cv;
    int nt = n >> 5;
    u16x4 o;
#pragma unroll
    for (int jv = 0; jv < 4; ++jv)
      o[jv] = f2bf(acc[jv][cv] * w8L[(tj * 4 + jv) * 2 + lh]);
    *(u16x4*)(Gtp + (size_t)(tk * 17 + nt) * 512 + ((n & 31) + 32 * khh) * 8 + jlo) = o;
  }
  // den rows (n = 512 + h, this block's 2 heads x 32 rows)
  if (t < 64) {
    int jj = t >> 1, lh2 = t & 1, h = 2 * y + lh2, j = j0 + jj;
    Gtp[(size_t)((j >> 4) * 17 + 16) * 512 + (h + 32 * ((jj & 15) >> 3)) * 8 + (jj & 7)] =
        f2bf(w8L[jj * 2 + lh2]);
  }
  // zero pad (n in [520,544)): slots [8,32) and [40,64) of tile nt=16
  if (y == 3 && t < 96) {
    int tk2 = t / 48, r = t - tk2 * 48;
    int slot = (r < 24) ? (8 + r) : (16 + r);
    u16x8 z = {0, 0, 0, 0, 0, 0, 0, 0};
    *(u16x8*)(Gtp + (size_t)(((j0 >> 4) + tk2) * 17 + 16) * 512 + slot * 8) = z;
  }
}

// ---------------------------------------------------------------------------
// Kernel 2: C += A(fp32,{0,1}) x G^T via 32x32x16 bf16 MFMA, atomicAdd into P.
// R5 inner structure (high-MLP: 10 B-load streams/dstep per wave), split-K
// Z=8: grid (64,8) = 512 blocks = 2 blocks/CU = 4 waves/SIMD at ~108 VGPR.
// __launch_bounds__(512,2): do NOT cap VGPR below need (R7's regression).
// ---------------------------------------------------------------------------
__global__ __launch_bounds__(512, 2) void k_gemm(const float* __restrict__ A,
                                                 const u16* __restrict__ Gtp,
                                                 float* __restrict__ P) {
  __shared__ __align__(16) u16 As[2][64 * 256];  // 2 x 32 KB
  const int t    = threadIdx.x;
  const int i0   = blockIdx.x * 64;
  const int kt0  = blockIdx.y * 512;
  const int w    = t >> 6, lane = t & 63;
  const int wr   = w >> 2, wc = w & 3;
  const int ml   = lane & 31, kh = lane >> 5;

  floatx16 acc[5];
#pragma unroll
  for (int q = 0; q < 5; ++q)
#pragma unroll
    for (int r = 0; r < 16; ++r) acc[q][r] = 0.f;

  // A staging: thread -> row ar (0..63), q-th float4 at k = (t&7)*4 + q*32
  const int ar  = t >> 3;
  const int af  = (t & 7) * 4;
  const float* pa = A + (size_t)(i0 + ar) * 4096 + kt0 + af;
  const int sbase = ar * 256 + (t & 1) * 4;   // + swizzled chunk*8
  const int scb   = (t & 7) >> 1;             // chunk = q*4 + scb
  const int arx   = ar & 7;

  // A-frag reads: row m = wr*32+ml, chunk c -> physical c^(ml&7)
  const int arow = (wr * 32 + ml) * 256;
  const int mx   = ml & 7;

  int nta[5];
#pragma unroll
  for (int q = 0; q < 5; ++q) { int v = wc + 4 * q; nta[q] = v < 17 ? v : 16; }

  float4 areg[8];
#pragma unroll
  for (int q = 0; q < 8; ++q) areg[q] = *(const float4*)(pa + q * 32);
#pragma unroll
  for (int q = 0; q < 8; ++q) {
    u16x4 v = {f2bf(areg[q].x), f2bf(areg[q].y), f2bf(areg[q].z), f2bf(areg[q].w)};
    *(u16x4*)(&As[0][sbase + ((q * 4 + scb) ^ arx) * 8]) = v;
  }
  __syncthreads();

  for (int cc = 0; cc < 2; ++cc) {
    const int cb = cc & 1;
    if (cc < 1) {                    // prefetch next chunk early (hidden by compute)
#pragma unroll
      for (int q = 0; q < 8; ++q)
        areg[q] = *(const float4*)(pa + (cc + 1) * 256 + q * 32);
    }
    const int ktb = (kt0 >> 4) + cc * 16;
#pragma unroll 2
    for (int ds = 0; ds < 8; ++ds) {
      short8 b0[5], b1[5];
#pragma unroll
      for (int q = 0; q < 5; ++q) {
        b0[q] = *(const short8*)(Gtp + (size_t)((ktb + ds * 2) * 17 + nta[q]) * 512 + lane * 8);
        b1[q] = *(const short8*)(Gtp + (size_t)((ktb + ds * 2 + 1) * 17 + nta[q]) * 512 + lane * 8);
      }
      short8 a0 = *(const short8*)(&As[cb][arow + ((ds * 4 + kh) ^ mx) * 8]);
      short8 a1 = *(const short8*)(&As[cb][arow + ((ds * 4 + 2 + kh) ^ mx) * 8]);
#pragma unroll
      for (int q = 0; q < 5; ++q)
        acc[q] = __builtin_amdgcn_mfma_f32_32x32x16_bf16(a0, b0[q], acc[q], 0, 0, 0);
#pragma unroll
      for (int q = 0; q < 5; ++q)
        acc[q] = __builtin_amdgcn_mfma_f32_32x32x16_bf16(a1, b1[q], acc[q], 0, 0, 0);
    }
    if (cc < 1) {
      __syncthreads();               // readers of other buffer done
#pragma unroll
      for (int q = 0; q < 8; ++q) {
        u16x4 v = {f2bf(areg[q].x), f2bf(areg[q].y), f2bf(areg[q].z), f2bf(areg[q].w)};
        *(u16x4*)(&As[cb ^ 1][sbase + ((q * 4 + scb) ^ arx) * 8]) = v;
      }
      __syncthreads();               // writes visible
    }
  }

  // epilogue: C/D layout col=lane&31, row=(r&3)+8*(r>>2)+4*(lane>>5); atomics
  const int rbase = i0 + wr * 32 + 4 * kh;
#pragma unroll
  for (int q = 0; q < 5; ++q) {
    int n = (wc + 4 * q) * 32 + ml;
    if (n < 520) {
#pragma unroll
      for (int r = 0; r < 16; ++r) {
        int row = rbase + (r & 3) + 8 * (r >> 2);
        atomicAdd(P + (size_t)row * 544 + n, acc[q][r]);
      }
    }
  }
}

// ---------------------------------------------------------------------------
// Kernel 3: out[i, u*8+h] = relu( P[i][h*64+u] / P[i][512+h] ). 2 rows/block.
// ---------------------------------------------------------------------------
__global__ __launch_bounds__(256) void k_out(const float* __restrict__ P,
                                             float* __restrict__ out) {
  __shared__ float ps[2][544];
  const int t    = threadIdx.x;
  const int half = t >> 7, lt = t & 127;
  const int i    = blockIdx.x * 2 + half;
  const float* pr = P + (size_t)i * 544;
  for (int q = lt; q < 544; q += 128) ps[half][q] = pr[q];
  __syncthreads();
  for (int c = lt; c < 512; c += 128) {           // c = u*8 + h
    int u = c >> 3, hd = c & 7;
    float o = ps[half][hd * 64 + u] / ps[half][512 + hd];
    out[(size_t)i * 512 + c] = fmaxf(o, 0.f);
  }
}

extern "C" void kernel_launch(void* const* d_in, const int* in_sizes, int n_in,
                              void* d_out, int out_size, void* d_ws, size_t ws_size,
                              hipStream_t stream) {
  const float* X  = (const float*)d_in[0];
  const float* A  = (const float*)d_in[1];
  const float* W  = (const float*)d_in[2];
  const float* av = (const float*)d_in[3];
  float* out = (float*)d_out;
  char*  ws  = (char*)d_ws;

  float* P   = (float*)ws;                 // 4096*544*4
  u16*   Gtp = (u16*)(ws + 8912896);       // 256*17 tiles * 1024 B

  k_hg<<<dim3(128, 4), 256, 0, stream>>>(X, W, av, Gtp, P);
  k_gemm<<<dim3(64, 8), 512, 0, stream>>>(A, Gtp, P);
  k_out<<<2048, 256, 0, stream>>>(P, out);
}